// Round 9
// baseline (40.510 us; speedup 1.0000x reference)
//
#include <hip/hip_runtime.h>
#include <hip/hip_bf16.h>

// Speculative-decoding acceptance. R8 post-mortem: our best copy phase is
// pinned at ~28us for 134MB (~4.8 TB/s eff) across 7 variants. R9 A/B: an
// EXTERNAL known-good mover on the exact same src/dst -- the ROCr blit via
// hipMemcpyAsync D2D (sanctioned for graph capture). Bulk copy is one
// contiguous range probs[0..512*V) -> out+521, so memcpy covers it fully
// (head/tail patches gone). Small kernels handle stats + acceptance + the 8
// n_match-dependent tail rows + ids.
//
// Pipeline: stats_kernel (288 blk) -> spec_kernel (33 blk) -> hipMemcpyAsync

#define NCHUNK 32
#define BLK 256
#define KFIX 8
#define NSTATS ((KFIX + 1) * NCHUNK)      // 288 stats units (9 rows x 32 chunks)

struct Ws {
    float pmax[16][NCHUNK];
    float psum[16][NCHUNK];
    int   pidx[16][NCHUNK];
};

struct MIS { float m; int i; float s; };

__device__ inline MIS mis_merge(MIS a, MIS b) {
    MIS r;
    r.i = (b.m > a.m || (b.m == a.m && b.i < a.i)) ? b.i : a.i;
    r.m = fmaxf(a.m, b.m);
    r.s = 0.0f;
    if (a.s > 0.0f) r.s += a.s * expf(a.m - r.m);   // guard nan from (-inf)-(-inf)
    if (b.s > 0.0f) r.s += b.s * expf(b.m - r.m);
    return r;
}

typedef float f4  __attribute__((ext_vector_type(4)));               // 16B-aligned
typedef float f4u __attribute__((ext_vector_type(4), aligned(4)));   // dword-aligned

__global__ __launch_bounds__(BLK)
void stats_kernel(const float* __restrict__ logits, Ws* __restrict__ ws, int V, int r) {
    __shared__ float sm[BLK];
    __shared__ int   si[BLK];
    __shared__ float ss[BLK];
    int t = threadIdx.x;
    int b = blockIdx.x;

    int ch = b & (NCHUNK - 1);
    int j  = b / NCHUNK;
    int chunk_elems = V / NCHUNK;              // 1004
    int cf4 = chunk_elems / 4;                 // 251
    int cbase = ch * chunk_elems;
    const float4* row = (const float4*)(logits + (size_t)(r - 1 + j) * V + cbase);

    float m = -INFINITY, s = 0.0f;
    int   mi = 0x7fffffff;
    for (int f = t; f < cf4; f += BLK) {
        float4 v = row[f];
        float vv[4] = {v.x, v.y, v.z, v.w};
        int c = cbase + f * 4;
        #pragma unroll
        for (int u = 0; u < 4; u++) {
            float x = vv[u];
            if (x > m) { s = s * expf(m - x) + 1.0f; m = x; mi = c + u; }
            else       { s += expf(x - m); }
        }
    }
    sm[t] = m; si[t] = mi; ss[t] = s;
    __syncthreads();
    for (int w = BLK >> 1; w > 0; w >>= 1) {
        if (t < w) {
            MIS a = {sm[t], si[t], ss[t]};
            MIS bb = {sm[t + w], si[t + w], ss[t + w]};
            MIS rr = mis_merge(a, bb);
            sm[t] = rr.m; si[t] = rr.i; ss[t] = rr.s;
        }
        __syncthreads();
    }
    if (t == 0) {
        ws->pmax[j][ch] = sm[0];
        ws->psum[j][ch] = ss[0];
        ws->pidx[j][ch] = si[0];
    }
}

// 33 blocks: b<32 -> tail row j=b>>2 quarter b&3; b==32 -> ids/n_match block.
__global__ __launch_bounds__(BLK)
void spec_kernel(const float* __restrict__ logits, const float* __restrict__ probs,
                 const int* __restrict__ ids, const int* __restrict__ leniency_p,
                 float* __restrict__ out, const Ws* __restrict__ ws,
                 int V, int r, int K, long long prob_off, long long out_last) {
    __shared__ float s_mx[12];
    __shared__ float s_sum[12];
    __shared__ int   s_amax[12];
    __shared__ int   s_draft[12];
    __shared__ int   s_acc[12];
    __shared__ int   s_nm;
    int t = threadIdx.x;
    int b = blockIdx.x;

    // self-merge stats (ws is L2-hot from stats_kernel)
    if (t <= K) {
        MIS acc = {ws->pmax[t][0], ws->pidx[t][0], ws->psum[t][0]};
        for (int c = 1; c < NCHUNK; c++) {
            MIS bb = {ws->pmax[t][c], ws->pidx[t][c], ws->psum[t][c]};
            acc = mis_merge(acc, bb);
        }
        s_mx[t] = acc.m; s_sum[t] = acc.s; s_amax[t] = acc.i;
    }
    __syncthreads();
    if (t < K) {
        int dj = ids[r + t];
        s_draft[t] = dj;
        size_t rowoff = (size_t)(r - 1 + t) * V;
        float tp = expf(logits[rowoff + dj] - s_mx[t]) / s_sum[t];
        float pp = probs[rowoff + dj];
        int   len = *leniency_p;
        bool eq      = (s_amax[t] == dj);
        bool lenient = (len > 1) && (tp > pp / (float)len);
        s_acc[t] = (eq || lenient) ? 1 : 0;
    }
    __syncthreads();
    if (t == 0) {
        int nm = 0;
        for (int q = 0; q < K; q++) { if (s_acc[q]) nm++; else break; }
        s_nm = nm;
    }
    __syncthreads();
    int nm = s_nm;

    if (b < 32) {
        // tail row j = b>>2, quarter sub = b&3 (out row r+j)
        int j = b >> 2, sub = b & 3;
        long long ob = prob_off + (long long)(r + j) * V;   // ob % 4 == 1
        const float* lg = logits + (size_t)(r - 1 + j) * V;
        bool on = (j < nm);
        float m   = s_mx[j];
        float inv = on ? (1.0f / s_sum[j]) : 0.0f;
        if (sub == 0) {
            if (t < 3)       out[ob + t]     = on ? expf(lg[t] - m) * inv : 0.0f;
            else if (t == 3) out[ob + V - 1] = on ? expf(lg[V - 1] - m) * inv : 0.0f;
        }
        int nf4r = (V - 4) / 4;                             // 8031
        int i0 = sub * 2008;
        int i1 = i0 + 2008; if (i1 > nf4r) i1 = nf4r;
        float* dst = out + ob + 3;
        const float* srcl = lg + 3;
        for (int i = i0 + t; i < i1; i += BLK) {
            f4 v;
            if (on) {
                f4u x = *reinterpret_cast<const f4u*>(srcl + 4 * (size_t)i);
                v.x = expf(x.x - m) * inv; v.y = expf(x.y - m) * inv;
                v.z = expf(x.z - m) * inv; v.w = expf(x.w - m) * inv;
            } else {
                v = (f4)0.0f;
            }
            *reinterpret_cast<f4*>(dst + 4 * (size_t)i) = v;
        }
    } else {
        // ids block: prefix, new_ids, n_match
        for (int i = t; i < r; i += BLK) out[i] = (float)ids[i];
        if (t <= K) {
            int v;
            if (t < nm)       v = s_draft[t];
            else if (t == nm) v = s_amax[t];
            else              v = 0;
            out[r + t] = (float)v;
        }
        if (t == K + 1) out[out_last] = (float)nm;
    }
}

extern "C" void kernel_launch(void* const* d_in, const int* in_sizes, int n_in,
                              void* d_out, int out_size, void* d_ws, size_t ws_size,
                              hipStream_t stream) {
    const float* logits     = (const float*)d_in[0];
    const float* probs      = (const float*)d_in[1];
    const int*   ids        = (const int*)d_in[2];
    const int*   leniency_p = (const int*)d_in[4];
    float* out = (float*)d_out;
    Ws*    ws  = (Ws*)d_ws;

    const int L = in_sizes[2];          // 520
    const int V = in_sizes[0] / L;      // 32128
    const int r = 512;                  // REVIEW_INDEX (problem constant)
    const int K = L - r;                // 8
    const long long prob_off = (long long)r + K + 1;   // 521
    const long long out_last = (long long)out_size - 1;

    // 1) stats partials (1.2 MB reads, ~2us)
    stats_kernel<<<NSTATS, BLK, 0, stream>>>(logits, ws, V, r);

    // 2) acceptance + tail rows + ids (~2us)
    spec_kernel<<<33, BLK, 0, stream>>>(logits, probs, ids, leniency_p, out, ws,
                                        V, r, K, prob_off, out_last);

    // 3) bulk copy via ROCr blit: probs[0 .. r*V) -> out[prob_off ..)
    hipMemcpyAsync(out + prob_off, probs, (size_t)r * V * sizeof(float),
                   hipMemcpyDeviceToDevice, stream);
}